// Round 3
// baseline (366.923 us; speedup 1.0000x reference)
//
#include <hip/hip_runtime.h>
#include <hip/hip_bf16.h>

#define NROWS 16384
#define DIM 64
#define TILE_COLS 128
#define CS 16                          // column splits
#define COLS_PER_BLOCK (NROWS / CS)    // 1024
#define TILES (COLS_PER_BLOCK / TILE_COLS)  // 8

static constexpr float TAU = 0.28f;
static constexpr float EPS = 1e-8f;
// exp(x/TAU) = exp2(x * EXP2_SCALE)
static constexpr float EXP2_SCALE = (float)(1.0 / (0.28 * 0.6931471805599453));
static constexpr float LN2F = 0.69314718055994530942f;

using short8 = __attribute__((ext_vector_type(8))) short;
using f32x4  = __attribute__((ext_vector_type(4))) float;

typedef __attribute__((address_space(1))) const unsigned char ga_t;
typedef __attribute__((address_space(3))) unsigned char la_t;

// Kernel 1: per-row L2 normalize; emit A = bf16(EXP2_SCALE * u_norm),
// W = bf16(u_norm + i_norm), p[n] = (u_norm . i_norm)/TAU, zero total[n].
__global__ __launch_bounds__(256) void prep_kernel(
    const float* __restrict__ u, const float* __restrict__ v,
    __hip_bfloat16* __restrict__ a_out, __hip_bfloat16* __restrict__ w_out,
    float* __restrict__ p_out, float* __restrict__ total)
{
    const int lane = threadIdx.x & 63;
    const int wv   = threadIdx.x >> 6;
    const int row  = blockIdx.x * 4 + wv;

    const float uu = u[row * DIM + lane];
    const float ii = v[row * DIM + lane];
    float su = uu * uu, si = ii * ii, sd = uu * ii;
#pragma unroll
    for (int m = 1; m < 64; m <<= 1) {
        su += __shfl_xor(su, m, 64);
        si += __shfl_xor(si, m, 64);
        sd += __shfl_xor(sd, m, 64);
    }
    const float inv_u = 1.0f / fmaxf(sqrtf(su), 1e-12f);
    const float inv_i = 1.0f / fmaxf(sqrtf(si), 1e-12f);
    const float un = uu * inv_u;
    const float in = ii * inv_i;
    a_out[row * DIM + lane] = __float2bfloat16(EXP2_SCALE * un);
    w_out[row * DIM + lane] = __float2bfloat16(un + in);
    if (lane == 0) {
        p_out[row] = sd * inv_u * inv_i * (1.0f / TAU);
        total[row] = 0.0f;
    }
}

// Kernel 2: fused GEMM + exp + row-sum, m97-style pipelined LDS staging.
// Grid: 1024 blocks = 64 row-groups (256 rows) x 16 col-splits (1024 cols).
// Block: 512 threads = 8 waves; wave w owns rows [rowgroup + w*32, +32).
// B tile (128 cols x 64 k, 16 KB) staged via global_load_lds (width 16) into
// a double buffer, XOR-swizzled chunks (c_phys = c ^ (j&7)) so ds_read_b128
// is 2-way-conflict-free. One barrier per tile: issue next-tile loads,
// compute current tile (~700 cyc) while they fly, then __syncthreads.
__global__ __launch_bounds__(512, 8) void score_kernel(
    const __hip_bfloat16* __restrict__ A, const __hip_bfloat16* __restrict__ W,
    float* __restrict__ total)
{
    __shared__ alignas(16) ushort buf[2][TILE_COLS * DIM];  // 2 x 16 KB

    const int tid  = threadIdx.x;
    const int lane = tid & 63;
    const int wv   = tid >> 6;          // 0..7
    const int l15  = lane & 15;
    const int quad = lane >> 4;
    const int rg   = blockIdx.x >> 4;   // 64 row-groups
    const int cs   = blockIdx.x & 15;   // 16 col-splits
    const int rowbase = rg * 256;
    const int col0    = cs * COLS_PER_BLOCK;

    const ushort* Au = (const ushort*)A;
    const ushort* Wu = (const ushort*)W;

    // A fragments: rows rowbase + wv*32 + rs*16 + l15, k = kk*32 + quad*8 + [0..7]
    short8 afrag[2][2];
#pragma unroll
    for (int rs = 0; rs < 2; rs++)
#pragma unroll
        for (int kk = 0; kk < 2; kk++)
            afrag[rs][kk] = *(const short8*)(
                Au + (size_t)(rowbase + wv * 32 + rs * 16 + l15) * DIM + kk * 32 + quad * 8);

    float rowsum[2][4];
#pragma unroll
    for (int rs = 0; rs < 2; rs++)
#pragma unroll
        for (int r = 0; r < 4; r++) rowsum[rs][r] = 0.0f;

    // Stage tile t into buf[b]: 1024 16-B chunks, 2 per thread.
    // Physical chunk p -> LDS offset p*16; global chunk c = c_phys ^ (j&7).
    auto stage = [&](int t, int b) {
#pragma unroll
        for (int q = 0; q < 2; q++) {
            const int p  = q * 512 + tid;
            const int j  = p >> 3;
            const int cg = (p & 7) ^ (j & 7);
            const ushort* g = Wu + (size_t)(col0 + t * TILE_COLS + j) * DIM + cg * 8;
            __builtin_amdgcn_global_load_lds((ga_t*)g, (la_t*)&buf[b][(size_t)p * 8], 16, 0, 0);
        }
    };

    stage(0, 0);
    __syncthreads();

    for (int t = 0; t < TILES; t++) {
        if (t + 1 < TILES) stage(t + 1, (t + 1) & 1);
        const ushort* lb = buf[t & 1];
#pragma unroll
        for (int cg = 0; cg < 8; cg++) {
            const int jl = cg * 16 + l15;
            const int sw = jl & 7;
            const short8 b0 = *(const short8*)&lb[(size_t)(jl * 8 + (quad ^ sw)) * 8];
            const short8 b1 = *(const short8*)&lb[(size_t)(jl * 8 + ((quad + 4) ^ sw)) * 8];
#pragma unroll
            for (int rs = 0; rs < 2; rs++) {
                f32x4 acc = {0.f, 0.f, 0.f, 0.f};
                acc = __builtin_amdgcn_mfma_f32_16x16x32_bf16(afrag[rs][0], b0, acc, 0, 0, 0);
                acc = __builtin_amdgcn_mfma_f32_16x16x32_bf16(afrag[rs][1], b1, acc, 0, 0, 0);
#pragma unroll
                for (int r = 0; r < 4; r++)
                    rowsum[rs][r] += __builtin_amdgcn_exp2f(acc[r]);
            }
        }
        __syncthreads();
    }

    // Reduce across the 16 columns held by lanes sharing a quad.
#pragma unroll
    for (int m = 1; m < 16; m <<= 1)
#pragma unroll
        for (int rs = 0; rs < 2; rs++)
#pragma unroll
            for (int r = 0; r < 4; r++)
                rowsum[rs][r] += __shfl_xor(rowsum[rs][r], m, 64);

    if (l15 == 0) {
#pragma unroll
        for (int rs = 0; rs < 2; rs++)
#pragma unroll
            for (int r = 0; r < 4; r++)
                atomicAdd(&total[rowbase + wv * 32 + rs * 16 + quad * 4 + r], rowsum[rs][r]);
    }
}

// Kernel 3: loss[n] = log(total[n] + EPS) - p[n]; out = mean.
__global__ __launch_bounds__(1024) void finalize_kernel(
    const float* __restrict__ total, const float* __restrict__ p,
    float* __restrict__ out)
{
    __shared__ float red[16];
    float s = 0.0f;
#pragma unroll
    for (int k = 0; k < NROWS / 1024; k++) {
        const int idx = k * 1024 + threadIdx.x;
        s += __log2f(total[idx] + EPS) * LN2F - p[idx];
    }
#pragma unroll
    for (int m = 1; m < 64; m <<= 1) s += __shfl_xor(s, m, 64);
    if ((threadIdx.x & 63) == 0) red[threadIdx.x >> 6] = s;
    __syncthreads();
    if (threadIdx.x == 0) {
        float t = 0.0f;
#pragma unroll
        for (int k = 0; k < 16; k++) t += red[k];
        out[0] = t * (1.0f / (float)NROWS);
    }
}

extern "C" void kernel_launch(void* const* d_in, const int* in_sizes, int n_in,
                              void* d_out, int out_size, void* d_ws, size_t ws_size,
                              hipStream_t stream) {
    const float* u = (const float*)d_in[0];
    const float* v = (const float*)d_in[1];

    char* ws = (char*)d_ws;
    __hip_bfloat16* a = (__hip_bfloat16*)(ws);                                  // 2 MB
    __hip_bfloat16* w = (__hip_bfloat16*)(ws + (size_t)NROWS * DIM * 2);        // 2 MB
    float* p   = (float*)(ws + (size_t)NROWS * DIM * 4);                        // 64 KB
    float* tot = (float*)(ws + (size_t)NROWS * DIM * 4 + (size_t)NROWS * 4);    // 64 KB

    prep_kernel<<<NROWS / 4, 256, 0, stream>>>(u, v, a, w, p, tot);
    score_kernel<<<64 * CS, 512, 0, stream>>>(a, w, tot);
    finalize_kernel<<<1, 1024, 0, stream>>>(tot, p, (float*)d_out);
}

// Round 4
// 103.944 us; speedup vs baseline: 3.5300x; 3.5300x over previous
//
#include <hip/hip_runtime.h>
#include <hip/hip_bf16.h>

#define NROWS 16384
#define DIM 64
#define BCOLS 512                     // cols per block: B tile = 64 KB LDS, staged ONCE
#define BROWS 1024                    // rows per block
#define NCS (NROWS / BCOLS)           // 32 col-splits
#define NRG (NROWS / BROWS)           // 16 row-groups

static constexpr float TAU = 0.28f;
static constexpr float EPS = 1e-8f;
// exp(x/TAU) = exp2(x * EXP2_SCALE); scale folded into A before bf16 cast.
static constexpr float EXP2_SCALE = (float)(1.0 / (0.28 * 0.6931471805599453));
static constexpr float LN2F = 0.69314718055994530942f;

using short8 = __attribute__((ext_vector_type(8))) short;
using f32x4  = __attribute__((ext_vector_type(4))) float;

typedef __attribute__((address_space(1))) const unsigned char ga_t;
typedef __attribute__((address_space(3))) unsigned char la_t;

// Kernel 1: per-row L2 normalize; emit A = bf16(EXP2_SCALE * u_norm),
// W = bf16(u_norm + i_norm), p[n] = (u_norm . i_norm)/TAU, zero total[n],
// zero d_out (it is consumed by finalize's atomicAdd).
__global__ __launch_bounds__(256) void prep_kernel(
    const float* __restrict__ u, const float* __restrict__ v,
    __hip_bfloat16* __restrict__ a_out, __hip_bfloat16* __restrict__ w_out,
    float* __restrict__ p_out, float* __restrict__ total, float* __restrict__ out)
{
    const int lane = threadIdx.x & 63;
    const int wv   = threadIdx.x >> 6;
    const int row  = blockIdx.x * 4 + wv;

    const float uu = u[row * DIM + lane];
    const float ii = v[row * DIM + lane];
    float su = uu * uu, si = ii * ii, sd = uu * ii;
#pragma unroll
    for (int m = 1; m < 64; m <<= 1) {
        su += __shfl_xor(su, m, 64);
        si += __shfl_xor(si, m, 64);
        sd += __shfl_xor(sd, m, 64);
    }
    const float inv_u = 1.0f / fmaxf(sqrtf(su), 1e-12f);
    const float inv_i = 1.0f / fmaxf(sqrtf(si), 1e-12f);
    const float un = uu * inv_u;
    const float in = ii * inv_i;
    a_out[row * DIM + lane] = __float2bfloat16(EXP2_SCALE * un);
    w_out[row * DIM + lane] = __float2bfloat16(un + in);
    if (lane == 0) {
        p_out[row] = sd * inv_u * inv_i * (1.0f / TAU);
        total[row] = 0.0f;
    }
    if (blockIdx.x == 0 && threadIdx.x == 0) out[0] = 0.0f;
}

// Kernel 2: fused GEMM + exp + row-sum.
// Grid: 512 blocks = 16 row-groups x 32 col-splits -> exactly 2 blocks/CU
// (LDS-capped), 4 waves/SIMD. Block: 512 threads = 8 waves.
// B tile (512 cols x 64 k = 64 KB) staged ONCE via global_load_lds (16 B),
// XOR-swizzled (chunk_phys = chunk ^ (col&7)) so every ds_read_b128 hits all
// 32 banks uniformly (8 accesses/bank = b128 floor). ONE barrier total.
// Each wave then streams 128 rows (4 steps of 32); the only in-loop global
// loads are 4 A-frag dwordx4 per step -> latency is irrelevant by volume.
__global__ __launch_bounds__(512, 4) void score_kernel(
    const __hip_bfloat16* __restrict__ A, const __hip_bfloat16* __restrict__ W,
    float* __restrict__ total)
{
    __shared__ alignas(16) ushort blds[BCOLS * DIM];   // exactly 64 KB

    const int tid  = threadIdx.x;
    const int lane = tid & 63;
    const int wv   = tid >> 6;          // 0..7
    const int l15  = lane & 15;
    const int quad = lane >> 4;
    const int cs   = blockIdx.x & (NCS - 1);
    const int rg   = blockIdx.x >> 5;
    const int col0    = cs * BCOLS;
    const int rowbase = rg * BROWS;

    const ushort* Au = (const ushort*)A;
    const ushort* Wu = (const ushort*)W;

    // Stage B: 4096 16-B chunks; physical slot p -> LDS offset p*16,
    // global chunk c = (p&7) ^ (col&7). Coalesced: each wave covers 8
    // contiguous 128-B cols (chunk order permuted within a col).
#pragma unroll
    for (int q = 0; q < 8; q++) {
        const int p = q * 512 + tid;
        const int j = p >> 3;
        const int c = (p & 7) ^ (j & 7);
        const ushort* g = Wu + (size_t)(col0 + j) * DIM + c * 8;
        __builtin_amdgcn_global_load_lds((ga_t*)g, (la_t*)&blds[(size_t)p * 8], 16, 0, 0);
    }
    __syncthreads();

    for (int si = 0; si < 4; si++) {
        const int r0 = rowbase + wv * 128 + si * 32;

        // A fragments: rows r0 + rs*16 + l15, k = kk*32 + quad*8 + [0..7]
        short8 af[2][2];
#pragma unroll
        for (int rs = 0; rs < 2; rs++)
#pragma unroll
            for (int kk = 0; kk < 2; kk++)
                af[rs][kk] = *(const short8*)(
                    Au + (size_t)(r0 + rs * 16 + l15) * DIM + kk * 32 + quad * 8);

        float rowsum[2][4];
#pragma unroll
        for (int rs = 0; rs < 2; rs++)
#pragma unroll
            for (int r = 0; r < 4; r++) rowsum[rs][r] = 0.0f;

#pragma unroll 8
        for (int ct = 0; ct < BCOLS / 16; ct++) {
            const int jl = ct * 16 + l15;
            const int sw = l15 & 7;     // (jl & 7) == (l15 & 7)
            const short8 b0 = *(const short8*)&blds[(size_t)(jl * 8 + (quad ^ sw)) * 8];
            const short8 b1 = *(const short8*)&blds[(size_t)(jl * 8 + ((4 + quad) ^ sw)) * 8];
#pragma unroll
            for (int rs = 0; rs < 2; rs++) {
                f32x4 acc = {0.f, 0.f, 0.f, 0.f};
                acc = __builtin_amdgcn_mfma_f32_16x16x32_bf16(af[rs][0], b0, acc, 0, 0, 0);
                acc = __builtin_amdgcn_mfma_f32_16x16x32_bf16(af[rs][1], b1, acc, 0, 0, 0);
#pragma unroll
                for (int r = 0; r < 4; r++)
                    rowsum[rs][r] += __builtin_amdgcn_exp2f(acc[r]);
            }
        }

        // Sum over the 16 columns held by each l15-group.
#pragma unroll
        for (int m = 1; m < 16; m <<= 1)
#pragma unroll
            for (int rs = 0; rs < 2; rs++)
#pragma unroll
                for (int r = 0; r < 4; r++)
                    rowsum[rs][r] += __shfl_xor(rowsum[rs][r], m, 64);

        if (l15 == 0) {
#pragma unroll
            for (int rs = 0; rs < 2; rs++)
#pragma unroll
                for (int r = 0; r < 4; r++)
                    atomicAdd(&total[r0 + rs * 16 + quad * 4 + r], rowsum[rs][r]);
        }
    }
}

// Kernel 3: out += mean(log(total + EPS) - p), parallel over 64 blocks.
__global__ __launch_bounds__(256) void finalize_kernel(
    const float* __restrict__ total, const float* __restrict__ p,
    float* __restrict__ out)
{
    __shared__ float red[4];
    const int idx = blockIdx.x * 256 + threadIdx.x;
    float s = __log2f(total[idx] + EPS) * LN2F - p[idx];
#pragma unroll
    for (int m = 1; m < 64; m <<= 1) s += __shfl_xor(s, m, 64);
    if ((threadIdx.x & 63) == 0) red[threadIdx.x >> 6] = s;
    __syncthreads();
    if (threadIdx.x == 0)
        atomicAdd(out, (red[0] + red[1] + red[2] + red[3]) * (1.0f / (float)NROWS));
}

extern "C" void kernel_launch(void* const* d_in, const int* in_sizes, int n_in,
                              void* d_out, int out_size, void* d_ws, size_t ws_size,
                              hipStream_t stream) {
    const float* u = (const float*)d_in[0];
    const float* v = (const float*)d_in[1];

    char* ws = (char*)d_ws;
    __hip_bfloat16* a = (__hip_bfloat16*)(ws);                                  // 2 MB
    __hip_bfloat16* w = (__hip_bfloat16*)(ws + (size_t)NROWS * DIM * 2);        // 2 MB
    float* p   = (float*)(ws + (size_t)NROWS * DIM * 4);                        // 64 KB
    float* tot = (float*)(ws + (size_t)NROWS * DIM * 4 + (size_t)NROWS * 4);    // 64 KB

    prep_kernel<<<NROWS / 4, 256, 0, stream>>>(u, v, a, w, p, tot, (float*)d_out);
    score_kernel<<<NRG * NCS, 512, 0, stream>>>(a, w, tot);
    finalize_kernel<<<NROWS / 256, 256, 0, stream>>>(tot, p, (float*)d_out);
}